// Round 5
// baseline (249.000 us; speedup 1.0000x reference)
//
#include <hip/hip_runtime.h>

#define Bsz 8
#define Ssz 128
#define Dsz 512
#define Lsz 512
#define Rsz 50
#define Mrows (Bsz * Ssz)          // 1024
#define SLOT (Mrows * Lsz)         // 524288 floats per ws slot
#define BSLOT (Lsz * Ssz)          // 65536: per-b stride of transposed slots
#define OUTMAT (Bsz * Ssz * Ssz)   // 131072

typedef __attribute__((ext_vector_type(8))) short bf16x8;
typedef __attribute__((ext_vector_type(4))) float f32x4;

union BFrag { unsigned u[4]; bf16x8 v; };

struct K1Args {
  const float* W1[4];
  const float* b1[4];
};

__device__ __forceinline__ float fast_tanh(float x) {
  float e = __expf(2.0f * x);
  return 1.0f - 2.0f * __builtin_amdgcn_rcpf(e + 1.0f);
}

__device__ __forceinline__ short f2bf(float x) {
  // RNE fp32 -> bf16 bits
  union { float f; unsigned u; } v; v.f = x;
  unsigned r = v.u + 0x7FFFu + ((v.u >> 16) & 1u);
  return (short)(r >> 16);
}

// pack two f32 -> (bf16(f0) | bf16(f1)<<16), round-half-up via +0x8000
__device__ __forceinline__ unsigned pk_bf16_rnd(float f0, float f1) {
  unsigned a = __float_as_uint(f0) + 0x8000u;
  unsigned b = __float_as_uint(f1) + 0x8000u;
  return __builtin_amdgcn_perm(b, a, 0x07060302);
}
// truncating pack (for hi-part of a hi/lo split)
__device__ __forceinline__ unsigned pk_bf16_trunc(float f0, float f1) {
  return __builtin_amdgcn_perm(__float_as_uint(f1), __float_as_uint(f0),
                               0x07060302);
}
__device__ __forceinline__ float bf_hi_f(float x) {
  return __uint_as_float(__float_as_uint(x) & 0xFFFF0000u);
}

// tanh(a+b) from ta=tanh(a), tb=tanh(b)
__device__ __forceinline__ float tpair(float ta, float tb) {
  return (ta + tb) * __builtin_amdgcn_rcpf(fmaf(ta, tb, 1.0f));
}

// ---------------------------------------------------------------------------
// Kernel 1: projections. A = x split hi/lo bf16 (exact to ~2^-16), B = W
// RNE bf16 (rel err ~2^-9, harmless pre-tanh) -> 2 MFMAs per product.
// Block tile 64m x 64n (grid 1024 wgs), wave tile 32m x 32n, K=512.
// Epilogue: +b1 (left only), tanh, store fp32.
//   Scalar-head slots (h<3) stored TRANSPOSED [b][l][idx]; label slots 6,7
//   row-major [m][l].
// ---------------------------------------------------------------------------
__global__ __launch_bounds__(256) void gemm_lr_mfma2(
    const float* __restrict__ x, K1Args a, float* __restrict__ ws) {
  const int side = blockIdx.z;
  const int h = side >> 1, r = side & 1;
  const float* __restrict__ W = a.W1[h] + r * (Dsz * Lsz);
  const float* __restrict__ bias = a.b1[h];
  const int tid = threadIdx.x;
  const int w = tid >> 6, lane = tid & 63;
  const int lm = lane & 15, q = lane >> 4;
  const int mw = blockIdx.y * 64 + (w & 1) * 32;
  const int nw = blockIdx.x * 64 + (w >> 1) * 32;

  f32x4 acc[2][2];
#pragma unroll
  for (int mt = 0; mt < 2; ++mt)
#pragma unroll
    for (int nt = 0; nt < 2; ++nt) {
      acc[mt][nt].x = 0.f; acc[mt][nt].y = 0.f;
      acc[mt][nt].z = 0.f; acc[mt][nt].w = 0.f;
    }

  for (int kc = 0; kc < Dsz; kc += 32) {
    const int k0 = kc + q * 8;
    BFrag ahi[2], alo[2];
#pragma unroll
    for (int mt = 0; mt < 2; ++mt) {
      const float* xp = x + (mw + mt * 16 + lm) * Dsz + k0;
      float4 v0 = *(const float4*)xp;
      float4 v1 = *(const float4*)(xp + 4);
      ahi[mt].u[0] = pk_bf16_trunc(v0.x, v0.y);
      ahi[mt].u[1] = pk_bf16_trunc(v0.z, v0.w);
      ahi[mt].u[2] = pk_bf16_trunc(v1.x, v1.y);
      ahi[mt].u[3] = pk_bf16_trunc(v1.z, v1.w);
      alo[mt].u[0] = pk_bf16_rnd(v0.x - bf_hi_f(v0.x), v0.y - bf_hi_f(v0.y));
      alo[mt].u[1] = pk_bf16_rnd(v0.z - bf_hi_f(v0.z), v0.w - bf_hi_f(v0.w));
      alo[mt].u[2] = pk_bf16_rnd(v1.x - bf_hi_f(v1.x), v1.y - bf_hi_f(v1.y));
      alo[mt].u[3] = pk_bf16_rnd(v1.z - bf_hi_f(v1.z), v1.w - bf_hi_f(v1.w));
    }
    BFrag bb[2];
#pragma unroll
    for (int nt = 0; nt < 2; ++nt) {
      const float* wp = W + k0 * Lsz + (nw + nt * 16 + lm);
      float vv[8];
#pragma unroll
      for (int jj = 0; jj < 8; ++jj) vv[jj] = wp[jj * Lsz];
      bb[nt].u[0] = pk_bf16_rnd(vv[0], vv[1]);
      bb[nt].u[1] = pk_bf16_rnd(vv[2], vv[3]);
      bb[nt].u[2] = pk_bf16_rnd(vv[4], vv[5]);
      bb[nt].u[3] = pk_bf16_rnd(vv[6], vv[7]);
    }
#pragma unroll
    for (int mt = 0; mt < 2; ++mt)
#pragma unroll
      for (int nt = 0; nt < 2; ++nt) {
        acc[mt][nt] = __builtin_amdgcn_mfma_f32_16x16x32_bf16(
            ahi[mt].v, bb[nt].v, acc[mt][nt], 0, 0, 0);
        acc[mt][nt] = __builtin_amdgcn_mfma_f32_16x16x32_bf16(
            alo[mt].v, bb[nt].v, acc[mt][nt], 0, 0, 0);
      }
  }

  float* slot = ws + side * SLOT;
  const bool transposed = (h < 3);   // all scalar-head sides
#pragma unroll
  for (int nt = 0; nt < 2; ++nt) {
    const int n_out = nw + nt * 16 + lm;
    const float bb_ = (r == 0) ? bias[n_out] : 0.0f;
#pragma unroll
    for (int mt = 0; mt < 2; ++mt) {
#pragma unroll
      for (int reg = 0; reg < 4; ++reg) {
        const int m_out = mw + mt * 16 + q * 4 + reg;
        float v;
        if (reg == 0) v = acc[mt][nt].x;
        else if (reg == 1) v = acc[mt][nt].y;
        else if (reg == 2) v = acc[mt][nt].z;
        else v = acc[mt][nt].w;
        const float t = fast_tanh(v + bb_);
        if (transposed) {
          const int bi = m_out >> 7, idx = m_out & 127;
          slot[bi * BSLOT + n_out * Ssz + idx] = t;
        } else {
          slot[m_out * Lsz + n_out] = t;
        }
      }
    }
  }
}

// ---------------------------------------------------------------------------
// Kernel 2: scalar heads via tanh-identity + LDS tiling.
// grid (16 tiles, 8 b, 3 heads); block 256 thr; tile 32i x 32j; thread 2x2.
// ---------------------------------------------------------------------------
__global__ __launch_bounds__(256) void pair_scalar3(
    const float* __restrict__ ws,
    const float* __restrict__ w2a, const float* __restrict__ w2b,
    const float* __restrict__ w2c,
    const float* __restrict__ b2a, const float* __restrict__ b2b,
    const float* __restrict__ b2c,
    float* __restrict__ out) {
  const int h = blockIdx.z;
  const int b = blockIdx.y;
  const int it = blockIdx.x >> 2, jt = blockIdx.x & 3;
  if (h == 0 && jt > it) return;   // span: strictly-upper tile
  const int i0 = it * 32, j0 = jt * 32;
  const int t = threadIdx.x;
  const int tj = t & 15, ti = t >> 4;

  const float* __restrict__ A  = ws + (2 * h) * SLOT + b * BSLOT;      // [l][i]
  const float* __restrict__ Bt = ws + (2 * h + 1) * SLOT + b * BSLOT;  // [l][j]
  const float* __restrict__ w2 = (h == 0) ? w2a : (h == 1 ? w2b : w2c);
  const float bias = (h == 0) ? b2a[0] : (h == 1 ? b2b[0] : b2c[0]);

  __shared__ float Ls[64][36];
  __shared__ float Rs[64][36];
  __shared__ float w2s[64];

  float acc00 = 0.f, acc01 = 0.f, acc10 = 0.f, acc11 = 0.f;

  const int sl = t >> 3;        // 0..31
  const int sf = (t & 7) * 4;   // 0,4,...,28

  for (int lc = 0; lc < Lsz; lc += 64) {
    __syncthreads();
    *(float4*)&Ls[sl][sf]      = *(const float4*)(A  + (lc + sl) * Ssz + i0 + sf);
    *(float4*)&Ls[sl + 32][sf] = *(const float4*)(A  + (lc + sl + 32) * Ssz + i0 + sf);
    *(float4*)&Rs[sl][sf]      = *(const float4*)(Bt + (lc + sl) * Ssz + j0 + sf);
    *(float4*)&Rs[sl + 32][sf] = *(const float4*)(Bt + (lc + sl + 32) * Ssz + j0 + sf);
    if (t < 64) w2s[t] = w2[lc + t];
    __syncthreads();
#pragma unroll 4
    for (int l = 0; l < 64; ++l) {
      const float2 ta = *(const float2*)&Ls[l][ti * 2];
      const float2 tb = *(const float2*)&Rs[l][tj * 2];
      const float wv = w2s[l];
      acc00 = fmaf(tpair(ta.x, tb.x), wv, acc00);
      acc01 = fmaf(tpair(ta.x, tb.y), wv, acc01);
      acc10 = fmaf(tpair(ta.y, tb.x), wv, acc10);
      acc11 = fmaf(tpair(ta.y, tb.y), wv, acc11);
    }
  }

  const int i = i0 + ti * 2, j = j0 + tj * 2;
  const float av[2][2] = {{acc00, acc01}, {acc10, acc11}};
  if (h == 0) {
#pragma unroll
    for (int di = 0; di < 2; ++di)
#pragma unroll
      for (int dj = 0; dj < 2; ++dj) {
        const int ii = i + di, jj = j + dj;
        if (jj <= ii) {
          const float v = av[di][dj] + bias;
          out[(b * Ssz + ii) * Ssz + jj] = v;
          out[(b * Ssz + jj) * Ssz + ii] = v;
        }
      }
  } else {
    float* o = out + h * OUTMAT;
    o[(b * Ssz + i) * Ssz + j]           = av[0][0] + bias;
    o[(b * Ssz + i) * Ssz + j + 1]       = av[0][1] + bias;
    o[(b * Ssz + i + 1) * Ssz + j]       = av[1][0] + bias;
    o[(b * Ssz + i + 1) * Ssz + j + 1]   = av[1][1] + bias;
  }
}

// ---------------------------------------------------------------------------
// Kernel 2.5: transpose + bf16-convert label W2 [512l][50o] -> [64o][512l].
// Output overwrites first 64KB of ws slot 0 (safe: pair_scalar3 is done).
// ---------------------------------------------------------------------------
__global__ __launch_bounds__(256) void w2prep(const float* __restrict__ W2,
                                              unsigned short* __restrict__ o) {
  int idx = blockIdx.x * 256 + threadIdx.x;  // 64*512 total
  int oo = idx >> 9, k = idx & 511;
  float v = (oo < Rsz) ? W2[k * Rsz + oo] : 0.0f;
  o[oo * Lsz + k] = (unsigned short)f2bf(v);
}

// ---------------------------------------------------------------------------
// Kernel 3: label head via bf16 MFMA + tanh-identity.
// grid (128 i, 8 b) = 1024 wgs; wave = 32-j-span (jb = wave*32):
// 2 m-tiles x 4 n-tiles, K=512. A-frags generated in-register with packed
// bf16 conversion (v_perm). 4096 waves -> 50% occupancy cap (2x R4).
// ---------------------------------------------------------------------------
__global__ __launch_bounds__(256) void pair_label3(
    const float* __restrict__ ws, const unsigned short* __restrict__ W2bfT,
    const float* __restrict__ b2, float* __restrict__ out) {
  const int b = blockIdx.y;
  const int i = blockIdx.x;
  const int tid = threadIdx.x;
  const int w = tid >> 6, lane = tid & 63;
  const int lm = lane & 15, q = lane >> 4;
  const int jb = w * 32;

  const float* Lrow = ws + 6 * SLOT + (b * Ssz + i) * Lsz;
  const float* Rbase = ws + 7 * SLOT + (long)b * Ssz * Lsz;
  float* out3 = out + 3 * OUTMAT;

  f32x4 acc[2][4];
#pragma unroll
  for (int mt = 0; mt < 2; ++mt)
#pragma unroll
    for (int nt = 0; nt < 4; ++nt) {
      acc[mt][nt].x = 0.f; acc[mt][nt].y = 0.f;
      acc[mt][nt].z = 0.f; acc[mt][nt].w = 0.f;
    }

  for (int kc = 0; kc < Lsz; kc += 32) {
    const int k0 = kc + q * 8;
    float4 lf0 = *(const float4*)(Lrow + k0);
    float4 lf1 = *(const float4*)(Lrow + k0 + 4);
    BFrag af[2];
#pragma unroll
    for (int mt = 0; mt < 2; ++mt) {
      const float* rp = Rbase + (jb + mt * 16 + lm) * Lsz + k0;
      float4 r0 = *(const float4*)rp;
      float4 r1 = *(const float4*)(rp + 4);
      af[mt].u[0] = pk_bf16_rnd(tpair(lf0.x, r0.x), tpair(lf0.y, r0.y));
      af[mt].u[1] = pk_bf16_rnd(tpair(lf0.z, r0.z), tpair(lf0.w, r0.w));
      af[mt].u[2] = pk_bf16_rnd(tpair(lf1.x, r1.x), tpair(lf1.y, r1.y));
      af[mt].u[3] = pk_bf16_rnd(tpair(lf1.z, r1.z), tpair(lf1.w, r1.w));
    }
    bf16x8 bfr[4];
#pragma unroll
    for (int nt = 0; nt < 4; ++nt)
      bfr[nt] = *(const bf16x8*)(W2bfT + (nt * 16 + lm) * Lsz + k0);
#pragma unroll
    for (int mt = 0; mt < 2; ++mt)
#pragma unroll
      for (int nt = 0; nt < 4; ++nt)
        acc[mt][nt] = __builtin_amdgcn_mfma_f32_16x16x32_bf16(
            af[mt].v, bfr[nt], acc[mt][nt], 0, 0, 0);
  }

#pragma unroll
  for (int nt = 0; nt < 4; ++nt) {
    const int o = nt * 16 + lm;
    if (o >= Rsz) continue;
    const float bias = b2[o];
#pragma unroll
    for (int mt = 0; mt < 2; ++mt) {
#pragma unroll
      for (int reg = 0; reg < 4; ++reg) {
        const int j = jb + mt * 16 + q * 4 + reg;
        const long base = ((long)(b * Ssz + i) * Ssz + j) * Rsz;
        float v;
        if (reg == 0) v = acc[mt][nt].x;
        else if (reg == 1) v = acc[mt][nt].y;
        else if (reg == 2) v = acc[mt][nt].z;
        else v = acc[mt][nt].w;
        out3[base + o] = v + bias;
      }
    }
  }
}

extern "C" void kernel_launch(void* const* d_in, const int* in_sizes, int n_in,
                              void* d_out, int out_size, void* d_ws,
                              size_t ws_size, hipStream_t stream) {
  (void)in_sizes; (void)n_in; (void)out_size; (void)ws_size;
  const float* x = (const float*)d_in[0];
  K1Args a;
  a.W1[0] = (const float*)d_in[1];  a.b1[0] = (const float*)d_in[2];
  a.W1[1] = (const float*)d_in[5];  a.b1[1] = (const float*)d_in[6];
  a.W1[2] = (const float*)d_in[9];  a.b1[2] = (const float*)d_in[10];
  a.W1[3] = (const float*)d_in[13]; a.b1[3] = (const float*)d_in[14];
  const float* w2a = (const float*)d_in[3];
  const float* b2a = (const float*)d_in[4];
  const float* w2b = (const float*)d_in[7];
  const float* b2b = (const float*)d_in[8];
  const float* w2c = (const float*)d_in[11];
  const float* b2c = (const float*)d_in[12];
  const float* W2l = (const float*)d_in[15];
  const float* b2l = (const float*)d_in[16];
  float* ws = (float*)d_ws;   // 8 slots x 2MB = 16MB (tanh'd projections)
  float* out = (float*)d_out;

  dim3 g1(Lsz / 64, Mrows / 64, 8);    // (8,16,8) = 1024 wgs
  gemm_lr_mfma2<<<g1, 256, 0, stream>>>(x, a, ws);
  dim3 g2(16, Bsz, 3);                 // (tiles, b, head)
  pair_scalar3<<<g2, 256, 0, stream>>>(ws, w2a, w2b, w2c, b2a, b2b, b2c, out);
  unsigned short* W2bfT = (unsigned short*)ws;  // reuses slot 0 (done)
  w2prep<<<(64 * Lsz) / 256, 256, 0, stream>>>(W2l, W2bfT);
  dim3 g3(Ssz, Bsz);                   // (128,8) = 1024 wgs
  pair_label3<<<g3, 256, 0, stream>>>(ws, W2bfT, b2l, out);
}

// Round 7
// 230.313 us; speedup vs baseline: 1.0811x; 1.0811x over previous
//
#include <hip/hip_runtime.h>

#define Bsz 8
#define Ssz 128
#define Dsz 512
#define D2 1024
#define Lsz 512
#define Rsz 50
#define Mrows 1024
#define SLOT 524288        // ushorts per slot (1 MB)
#define BSLOT 65536        // per-b stride in transposed slots (ushorts)
#define OUTMAT 131072

typedef __attribute__((ext_vector_type(8))) _Float16 f16x8;
typedef __attribute__((ext_vector_type(2))) __fp16 fp16x2;
typedef __attribute__((ext_vector_type(4))) float f32x4;

union UV4 { uint4 u; f16x8 h; };
union UH { unsigned short s; _Float16 h; };
union UP { fp16x2 h; unsigned u; };

struct K1Args {
  const float* W1[4];
  const float* b1[4];
};

__device__ __forceinline__ float f16lo(unsigned u) {
  UH x; x.s = (unsigned short)(u & 0xffffu); return (float)x.h;
}
__device__ __forceinline__ float f16hi(unsigned u) {
  UH x; x.s = (unsigned short)(u >> 16); return (float)x.h;
}
__device__ __forceinline__ unsigned pkrtz(float a, float b) {
  UP c; c.h = __builtin_amdgcn_cvt_pkrtz(a, b); return c.u;
}
__device__ __forceinline__ unsigned short f2h(float v) {
  UH x; x.h = (_Float16)v; return x.s;
}
__device__ __forceinline__ float fast_tanh(float x) {
  float e = __expf(2.0f * x);
  return 1.0f - 2.0f * __builtin_amdgcn_rcpf(e + 1.0f);
}
// tanh(a+b) from ta=tanh(a), tb=tanh(b)
__device__ __forceinline__ float tpair(float ta, float tb) {
  return (ta + tb) * __builtin_amdgcn_rcpf(fmaf(ta, tb, 1.0f));
}

// ---------------------------------------------------------------------------
// Prep: z<4 -> transpose+f16 W1[z] [1024k][512n] -> W1T [512n][1024k];
//       z==4 -> straight f16 convert of x [1024][512].
// ---------------------------------------------------------------------------
__global__ __launch_bounds__(256) void prep_w1x(
    const float* __restrict__ x, K1Args a,
    unsigned short* __restrict__ W1T, unsigned short* __restrict__ X16) {
  const int z = blockIdx.z;
  const int t = threadIdx.x;
  if (z < 4) {
    __shared__ float S[64][65];
    const float* __restrict__ W = a.W1[z];
    const int n0 = blockIdx.x * 64;
    const int k0 = blockIdx.y * 64;
    {
      const int kk = t >> 2, c16 = (t & 3) * 16;
      const float* p = W + (k0 + kk) * Lsz + n0 + c16;
#pragma unroll
      for (int c = 0; c < 4; ++c) {
        float4 v = *(const float4*)(p + c * 4);
        S[kk][c16 + c * 4 + 0] = v.x; S[kk][c16 + c * 4 + 1] = v.y;
        S[kk][c16 + c * 4 + 2] = v.z; S[kk][c16 + c * 4 + 3] = v.w;
      }
    }
    __syncthreads();
    {
      const int nn = t >> 2, kb = (t & 3) * 16;
      unsigned pk[8];
#pragma unroll
      for (int e = 0; e < 8; ++e)
        pk[e] = pkrtz(S[kb + 2 * e][nn], S[kb + 2 * e + 1][nn]);
      unsigned short* o = W1T + z * (Lsz * D2) + (n0 + nn) * D2 + k0 + kb;
      *(uint4*)(o) = make_uint4(pk[0], pk[1], pk[2], pk[3]);
      *(uint4*)(o + 8) = make_uint4(pk[4], pk[5], pk[6], pk[7]);
    }
  } else {
    const int wid = blockIdx.y * 8 + blockIdx.x;   // 0..127
    const int base = wid * 4096 + t * 16;
    const float* p = x + base;
    float4 v0 = *(const float4*)p, v1 = *(const float4*)(p + 4);
    float4 v2 = *(const float4*)(p + 8), v3 = *(const float4*)(p + 12);
    uint4 o0 = make_uint4(pkrtz(v0.x, v0.y), pkrtz(v0.z, v0.w),
                          pkrtz(v1.x, v1.y), pkrtz(v1.z, v1.w));
    uint4 o1 = make_uint4(pkrtz(v2.x, v2.y), pkrtz(v2.z, v2.w),
                          pkrtz(v3.x, v3.y), pkrtz(v3.z, v3.w));
    *(uint4*)(X16 + base) = o0;
    *(uint4*)(X16 + base + 8) = o1;
  }
}

// ---------------------------------------------------------------------------
// Prep: label W2 [512k][50o] fp32 -> W2T f16 [64o][512k] (zero-padded).
// ---------------------------------------------------------------------------
__global__ __launch_bounds__(256) void w2prep_h(const float* __restrict__ W2,
                                                unsigned short* __restrict__ W2T) {
  int idx = blockIdx.x * 256 + threadIdx.x;  // 64*512
  int oo = idx >> 9, k = idx & 511;
  float v = (oo < Rsz) ? W2[k * Rsz + oo] : 0.0f;
  W2T[oo * Lsz + k] = f2h(v);
}

// ---------------------------------------------------------------------------
// Kernel 1: projections, pure f16 MFMA (contiguous frags both sides).
// Block 64m x 64n, wave 32x32, K=512 (side r uses k-range r*512..+512 of W1T).
// Epilogue: +b1 (left only), tanh, f16 store.
//   Scalar-head slots (h<3): transposed [b][n][i] (4 consecutive i per store).
//   Label slots 6,7: row-major [m][n].
// ---------------------------------------------------------------------------
__global__ __launch_bounds__(256) void gemm_lr_f16(
    const unsigned short* __restrict__ X16,
    const unsigned short* __restrict__ W1T, K1Args a,
    unsigned short* __restrict__ U) {
  const int side = blockIdx.z;
  const int h = side >> 1, r = side & 1;
  const unsigned short* __restrict__ Bt = W1T + h * (Lsz * D2);
  const float* __restrict__ bias = a.b1[h];
  const int tid = threadIdx.x;
  const int w = tid >> 6, lane = tid & 63;
  const int lm = lane & 15, q = lane >> 4;
  const int mw = blockIdx.y * 64 + (w & 1) * 32;
  const int nw = blockIdx.x * 64 + (w >> 1) * 32;

  f32x4 acc[2][2];
#pragma unroll
  for (int mt = 0; mt < 2; ++mt)
#pragma unroll
    for (int nt = 0; nt < 2; ++nt) {
      acc[mt][nt].x = 0.f; acc[mt][nt].y = 0.f;
      acc[mt][nt].z = 0.f; acc[mt][nt].w = 0.f;
    }

  for (int kc = 0; kc < Dsz; kc += 32) {
    const int k0 = kc + q * 8;
    UV4 af[2], bf[2];
#pragma unroll
    for (int mt = 0; mt < 2; ++mt)
      af[mt].u = *(const uint4*)(X16 + (mw + mt * 16 + lm) * Dsz + k0);
#pragma unroll
    for (int nt = 0; nt < 2; ++nt)
      bf[nt].u = *(const uint4*)(Bt + (nw + nt * 16 + lm) * D2 + r * Dsz + k0);
#pragma unroll
    for (int mt = 0; mt < 2; ++mt)
#pragma unroll
      for (int nt = 0; nt < 2; ++nt)
        acc[mt][nt] = __builtin_amdgcn_mfma_f32_16x16x32_f16(
            af[mt].h, bf[nt].h, acc[mt][nt], 0, 0, 0);
  }

  unsigned short* slot = U + side * SLOT;
  if (h < 3) {
#pragma unroll
    for (int nt = 0; nt < 2; ++nt) {
      const int n_out = nw + nt * 16 + lm;
      const float bb = (r == 0) ? bias[n_out] : 0.0f;
#pragma unroll
      for (int mt = 0; mt < 2; ++mt) {
        const int m0r = mw + mt * 16 + q * 4;
        const float t0 = fast_tanh(acc[mt][nt].x + bb);
        const float t1 = fast_tanh(acc[mt][nt].y + bb);
        const float t2 = fast_tanh(acc[mt][nt].z + bb);
        const float t3 = fast_tanh(acc[mt][nt].w + bb);
        uint2 pr;
        pr.x = pkrtz(t0, t1);
        pr.y = pkrtz(t2, t3);
        const int bi = m0r >> 7, il = m0r & 127;
        *(uint2*)(slot + bi * BSLOT + n_out * Ssz + il) = pr;
      }
    }
  } else {
#pragma unroll
    for (int nt = 0; nt < 2; ++nt) {
      const int n_out = nw + nt * 16 + lm;
      const float bb = (r == 0) ? bias[n_out] : 0.0f;
#pragma unroll
      for (int mt = 0; mt < 2; ++mt) {
#pragma unroll
        for (int reg = 0; reg < 4; ++reg) {
          const int m_out = mw + mt * 16 + q * 4 + reg;
          float v;
          if (reg == 0) v = acc[mt][nt].x;
          else if (reg == 1) v = acc[mt][nt].y;
          else if (reg == 2) v = acc[mt][nt].z;
          else v = acc[mt][nt].w;
          slot[m_out * Lsz + n_out] = f2h(fast_tanh(v + bb));
        }
      }
    }
  }
}

// ---------------------------------------------------------------------------
// Kernel 2: scalar heads, tanh-identity + f16 LDS tiling. 32i x 32j tile,
// 2x2/thread.
// ---------------------------------------------------------------------------
__global__ __launch_bounds__(256) void pair_scalar4(
    const unsigned short* __restrict__ U,
    const float* __restrict__ w2a, const float* __restrict__ w2b,
    const float* __restrict__ w2c,
    const float* __restrict__ b2a, const float* __restrict__ b2b,
    const float* __restrict__ b2c,
    float* __restrict__ out) {
  const int h = blockIdx.z;
  const int b = blockIdx.y;
  const int it = blockIdx.x >> 2, jt = blockIdx.x & 3;
  if (h == 0 && jt > it) return;
  const int i0 = it * 32, j0 = jt * 32;
  const int t = threadIdx.x;
  const int tj = t & 15, ti = t >> 4;

  const unsigned short* __restrict__ A  = U + (2 * h) * SLOT + b * BSLOT;
  const unsigned short* __restrict__ Bt = U + (2 * h + 1) * SLOT + b * BSLOT;
  const float* __restrict__ w2 = (h == 0) ? w2a : (h == 1 ? w2b : w2c);
  const float bias = (h == 0) ? b2a[0] : (h == 1 ? b2b[0] : b2c[0]);

  __shared__ unsigned short Ls[64][40];
  __shared__ unsigned short Rs[64][40];
  __shared__ float w2s[64];

  float acc00 = 0.f, acc01 = 0.f, acc10 = 0.f, acc11 = 0.f;
  const int sr = t >> 2;        // 0..63
  const int sc = (t & 3) * 8;   // 0,8,16,24

  for (int lc = 0; lc < Lsz; lc += 64) {
    __syncthreads();
    *(uint4*)&Ls[sr][sc] = *(const uint4*)(A + (lc + sr) * Ssz + i0 + sc);
    *(uint4*)&Rs[sr][sc] = *(const uint4*)(Bt + (lc + sr) * Ssz + j0 + sc);
    if (t < 64) w2s[t] = w2[lc + t];
    __syncthreads();
#pragma unroll 4
    for (int l = 0; l < 64; ++l) {
      const unsigned ua = *(const unsigned*)&Ls[l][ti * 2];
      const unsigned ub = *(const unsigned*)&Rs[l][tj * 2];
      const float tax = f16lo(ua), tay = f16hi(ua);
      const float tbx = f16lo(ub), tby = f16hi(ub);
      const float wv = w2s[l];
      acc00 = fmaf(tpair(tax, tbx), wv, acc00);
      acc01 = fmaf(tpair(tax, tby), wv, acc01);
      acc10 = fmaf(tpair(tay, tbx), wv, acc10);
      acc11 = fmaf(tpair(tay, tby), wv, acc11);
    }
  }

  const int i = i0 + ti * 2, j = j0 + tj * 2;
  const float av[2][2] = {{acc00, acc01}, {acc10, acc11}};
  if (h == 0) {
#pragma unroll
    for (int di = 0; di < 2; ++di)
#pragma unroll
      for (int dj = 0; dj < 2; ++dj) {
        const int ii = i + di, jj = j + dj;
        if (jj <= ii) {
          const float v = av[di][dj] + bias;
          out[(b * Ssz + ii) * Ssz + jj] = v;
          out[(b * Ssz + jj) * Ssz + ii] = v;
        }
      }
  } else {
    float* o = out + h * OUTMAT;
    o[(b * Ssz + i) * Ssz + j]         = av[0][0] + bias;
    o[(b * Ssz + i) * Ssz + j + 1]     = av[0][1] + bias;
    o[(b * Ssz + i + 1) * Ssz + j]     = av[1][0] + bias;
    o[(b * Ssz + i + 1) * Ssz + j + 1] = av[1][1] + bias;
  }
}

// ---------------------------------------------------------------------------
// Kernel 3: label head, f16 MFMA + tanh-identity + software pipeline.
// wg = 4 waves; 2 i's per wg (shared R and B frags); wave = 16 j x 64 o,
// K=512. R/L prefetched one K-iter ahead. Grid (64,2,8) = 1024 wgs.
// ---------------------------------------------------------------------------
__global__ __launch_bounds__(256) void pair_label5(
    const unsigned short* __restrict__ U,
    const unsigned short* __restrict__ W2T,
    const float* __restrict__ b2, float* __restrict__ out) {
  const int b = blockIdx.z;
  const int i0 = blockIdx.x * 2;
  const int tid = threadIdx.x;
  const int w = tid >> 6, lane = tid & 63;
  const int lm = lane & 15, q = lane >> 4;
  const int jb = blockIdx.y * 64 + w * 16;

  const unsigned short* __restrict__ L0 = U + 6 * SLOT + (b * Ssz + i0) * Lsz;
  const unsigned short* __restrict__ L1 = L0 + Lsz;
  const unsigned short* __restrict__ Rr = U + 7 * SLOT + (b * Ssz + jb + lm) * Lsz;
  const unsigned short* __restrict__ Bp = W2T + lm * Lsz;
  float* out3 = out + 3 * OUTMAT;

  f32x4 acc[2][4];
#pragma unroll
  for (int ii = 0; ii < 2; ++ii)
#pragma unroll
    for (int nt = 0; nt < 4; ++nt) {
      acc[ii][nt].x = 0.f; acc[ii][nt].y = 0.f;
      acc[ii][nt].z = 0.f; acc[ii][nt].w = 0.f;
    }

  const int kq = q * 8;
  uint4 rc  = *(const uint4*)(Rr + kq);
  uint4 l0c = *(const uint4*)(L0 + kq);
  uint4 l1c = *(const uint4*)(L1 + kq);

#pragma unroll 1
  for (int kc = 0; kc < Lsz; kc += 32) {
    const int kn = ((kc + 32) & 511) + kq;
    uint4 rn  = *(const uint4*)(Rr + kn);
    uint4 l0n = *(const uint4*)(L0 + kn);
    uint4 l1n = *(const uint4*)(L1 + kn);
    UV4 bf[4];
#pragma unroll
    for (int nt = 0; nt < 4; ++nt)
      bf[nt].u = *(const uint4*)(Bp + nt * 16 * Lsz + kc + kq);

    float rf[8] = {f16lo(rc.x), f16hi(rc.x), f16lo(rc.y), f16hi(rc.y),
                   f16lo(rc.z), f16hi(rc.z), f16lo(rc.w), f16hi(rc.w)};
    float a0[8] = {f16lo(l0c.x), f16hi(l0c.x), f16lo(l0c.y), f16hi(l0c.y),
                   f16lo(l0c.z), f16hi(l0c.z), f16lo(l0c.w), f16hi(l0c.w)};
    float a1[8] = {f16lo(l1c.x), f16hi(l1c.x), f16lo(l1c.y), f16hi(l1c.y),
                   f16lo(l1c.z), f16hi(l1c.z), f16lo(l1c.w), f16hi(l1c.w)};
    UV4 A0, A1;
    A0.u = make_uint4(pkrtz(tpair(a0[0], rf[0]), tpair(a0[1], rf[1])),
                      pkrtz(tpair(a0[2], rf[2]), tpair(a0[3], rf[3])),
                      pkrtz(tpair(a0[4], rf[4]), tpair(a0[5], rf[5])),
                      pkrtz(tpair(a0[6], rf[6]), tpair(a0[7], rf[7])));
    A1.u = make_uint4(pkrtz(tpair(a1[0], rf[0]), tpair(a1[1], rf[1])),
                      pkrtz(tpair(a1[2], rf[2]), tpair(a1[3], rf[3])),
                      pkrtz(tpair(a1[4], rf[4]), tpair(a1[5], rf[5])),
                      pkrtz(tpair(a1[6], rf[6]), tpair(a1[7], rf[7])));
#pragma unroll
    for (int nt = 0; nt < 4; ++nt) {
      acc[0][nt] = __builtin_amdgcn_mfma_f32_16x16x32_f16(
          A0.h, bf[nt].h, acc[0][nt], 0, 0, 0);
      acc[1][nt] = __builtin_amdgcn_mfma_f32_16x16x32_f16(
          A1.h, bf[nt].h, acc[1][nt], 0, 0, 0);
    }
    rc = rn; l0c = l0n; l1c = l1n;
  }

#pragma unroll
  for (int nt = 0; nt < 4; ++nt) {
    const int o = nt * 16 + lm;
    if (o >= Rsz) continue;
    const float bias = b2[o];
#pragma unroll
    for (int ii = 0; ii < 2; ++ii) {
#pragma unroll
      for (int reg = 0; reg < 4; ++reg) {
        const int j = jb + q * 4 + reg;
        const long base = ((long)((b * Ssz + i0 + ii) * Ssz) + j) * Rsz;
        float v;
        if (reg == 0) v = acc[ii][nt].x;
        else if (reg == 1) v = acc[ii][nt].y;
        else if (reg == 2) v = acc[ii][nt].z;
        else v = acc[ii][nt].w;
        out3[base + o] = v + bias;
      }
    }
  }
}

extern "C" void kernel_launch(void* const* d_in, const int* in_sizes, int n_in,
                              void* d_out, int out_size, void* d_ws,
                              size_t ws_size, hipStream_t stream) {
  (void)in_sizes; (void)n_in; (void)out_size; (void)ws_size;
  const float* x = (const float*)d_in[0];
  K1Args a;
  a.W1[0] = (const float*)d_in[1];  a.b1[0] = (const float*)d_in[2];
  a.W1[1] = (const float*)d_in[5];  a.b1[1] = (const float*)d_in[6];
  a.W1[2] = (const float*)d_in[9];  a.b1[2] = (const float*)d_in[10];
  a.W1[3] = (const float*)d_in[13]; a.b1[3] = (const float*)d_in[14];
  const float* w2a = (const float*)d_in[3];
  const float* b2a = (const float*)d_in[4];
  const float* w2b = (const float*)d_in[7];
  const float* b2b = (const float*)d_in[8];
  const float* w2c = (const float*)d_in[11];
  const float* b2c = (const float*)d_in[12];
  const float* W2l = (const float*)d_in[15];
  const float* b2l = (const float*)d_in[16];
  float* out = (float*)d_out;

  // ws layout (ushorts): [0,8*SLOT): 8 f16 slots (scalar heads transposed
  // [b][l][idx]; label 6,7 row-major [m][l]). [8*SLOT, +4MB): W1T f16
  // [h][512n][1024k]. then X16 f16 [1024][512], then W2T f16 [64][512].
  unsigned short* U   = (unsigned short*)d_ws;
  unsigned short* W1T = U + 8 * SLOT;
  unsigned short* X16 = U + 8 * SLOT + 4 * (Lsz * D2);
  unsigned short* W2T = U + 8 * SLOT + 5 * (Lsz * D2);

  prep_w1x<<<dim3(8, 16, 5), 256, 0, stream>>>(x, a, W1T, X16);
  w2prep_h<<<(64 * Lsz) / 256, 256, 0, stream>>>(W2l, W2T);
  gemm_lr_f16<<<dim3(8, 16, 8), 256, 0, stream>>>(X16, W1T, a, U);
  pair_scalar4<<<dim3(16, Bsz, 3), 256, 0, stream>>>(U, w2a, w2b, w2c,
                                                     b2a, b2b, b2c, out);
  pair_label5<<<dim3(64, 2, Bsz), 256, 0, stream>>>(U, W2T, b2l, out);
}

// Round 8
// 166.473 us; speedup vs baseline: 1.4957x; 1.3835x over previous
//
#include <hip/hip_runtime.h>

#define Bsz 8
#define Ssz 128
#define Dsz 512
#define D2 1024
#define Lsz 512
#define Rsz 50
#define SLOT 524288        // ushorts per slot (1 MB)
#define BSLOT 65536        // per-b stride in transposed slots (ushorts)
#define OUTMAT 131072

typedef __attribute__((ext_vector_type(8))) _Float16 f16x8;
typedef __attribute__((ext_vector_type(2))) __fp16 fp16x2;
typedef __attribute__((ext_vector_type(4))) float f32x4;

union UV4 { uint4 u; f16x8 h; };
union UH { unsigned short s; _Float16 h; };
union UP { fp16x2 h; unsigned u; };

struct K1Args {
  const float* W1[4];
  const float* b1[4];
};

__device__ __forceinline__ float f16lo(unsigned u) {
  UH x; x.s = (unsigned short)(u & 0xffffu); return (float)x.h;
}
__device__ __forceinline__ float f16hi(unsigned u) {
  UH x; x.s = (unsigned short)(u >> 16); return (float)x.h;
}
__device__ __forceinline__ unsigned pkrtz(float a, float b) {
  UP c; c.h = __builtin_amdgcn_cvt_pkrtz(a, b); return c.u;
}
__device__ __forceinline__ unsigned short f2h(float v) {
  UH x; x.h = (_Float16)v; return x.s;
}
__device__ __forceinline__ float rcpf(float x) {
  return __builtin_amdgcn_rcpf(x);
}

// ---------------------------------------------------------------------------
// Prep: z<4: W1[z] [1024k][512n] fp32 -> W1F f16 in MFMA-fragment order:
//   frag(h, nt in [0,32), kb in [0,32)) = 64 lanes x 8 f16 (n=lane&15,
//   k=kb*32+(lane>>4)*8+e), contiguous 1KB per frag.
// z==4: x [1024m][512k] fp32 -> X16F f16 frag order (mt in [0,64), kb in
//   [0,16)).
// ---------------------------------------------------------------------------
__global__ __launch_bounds__(256) void prep_all(
    const float* __restrict__ x, K1Args a,
    unsigned short* __restrict__ W1F, unsigned short* __restrict__ X16F) {
  const int z = blockIdx.z;
  const int t = threadIdx.x;
  if (z < 4) {
    if (blockIdx.x >= 8) return;
    __shared__ float S[64][65];
    const float* __restrict__ W = a.W1[z];
    const int n0 = blockIdx.x * 64;
    const int k0 = blockIdx.y * 64;
    {
      const int kk = t >> 2, c16 = (t & 3) * 16;
      const float* p = W + (k0 + kk) * Lsz + n0 + c16;
#pragma unroll
      for (int c = 0; c < 4; ++c) {
        float4 v = *(const float4*)(p + c * 4);
        S[kk][c16 + c * 4 + 0] = v.x; S[kk][c16 + c * 4 + 1] = v.y;
        S[kk][c16 + c * 4 + 2] = v.z; S[kk][c16 + c * 4 + 3] = v.w;
      }
    }
    __syncthreads();
#pragma unroll
    for (int o = t; o < 512; o += 256) {
      const int lane = o & 63;
      const int ntl = (o >> 6) & 3, kbl = o >> 8;
      const int n_l = ntl * 16 + (lane & 15);
      const int k_l = kbl * 32 + (lane >> 4) * 8;
      uint4 pk;
      pk.x = pkrtz(S[k_l + 0][n_l], S[k_l + 1][n_l]);
      pk.y = pkrtz(S[k_l + 2][n_l], S[k_l + 3][n_l]);
      pk.z = pkrtz(S[k_l + 4][n_l], S[k_l + 5][n_l]);
      pk.w = pkrtz(S[k_l + 6][n_l], S[k_l + 7][n_l]);
      const long addr =
          ((long)((z * 32 + blockIdx.x * 4 + ntl) * 32 + blockIdx.y * 2 + kbl) *
               64 + lane) * 8;
      *(uint4*)(W1F + addr) = pk;
    }
  } else {
    const int idx = (blockIdx.y * 16 + blockIdx.x) * 256 + t;  // [0,65536)
    const int frag = idx >> 6, lane = idx & 63;
    const int m = (frag >> 4) * 16 + (lane & 15);
    const int k0 = (frag & 15) * 32 + (lane >> 4) * 8;
    const float* p = x + m * Dsz + k0;
    float4 v0 = *(const float4*)p, v1 = *(const float4*)(p + 4);
    uint4 pk = make_uint4(pkrtz(v0.x, v0.y), pkrtz(v0.z, v0.w),
                          pkrtz(v1.x, v1.y), pkrtz(v1.z, v1.w));
    *(uint4*)(X16F + (long)idx * 8) = pk;
  }
}

// ---------------------------------------------------------------------------
// Prep: label W2 [512k][50o] fp32 -> W2F f16 fragment order
// (ot in [0,4), kb in [0,16)), o zero-padded to 64.
// ---------------------------------------------------------------------------
__global__ __launch_bounds__(256) void w2prep_f(const float* __restrict__ W2,
                                                unsigned short* __restrict__ W2F) {
  const int idx = blockIdx.x * 256 + threadIdx.x;  // [0,4096)
  const int frag = idx >> 6, lane = idx & 63;
  const int o = (frag >> 4) * 16 + (lane & 15);
  const int k0 = (frag & 15) * 32 + (lane >> 4) * 8;
  float v[8];
#pragma unroll
  for (int e = 0; e < 8; ++e)
    v[e] = (o < Rsz) ? W2[(k0 + e) * Rsz + o] : 0.0f;
  uint4 pk = make_uint4(pkrtz(v[0], v[1]), pkrtz(v[2], v[3]),
                        pkrtz(v[4], v[5]), pkrtz(v[6], v[7]));
  *(uint4*)(W2F + (long)idx * 8) = pk;
}

// ---------------------------------------------------------------------------
// Kernel 1: projections, pure f16 MFMA, all K-loop loads coalesced (fragment
// order). Block 64m x 64n, wave 32x32, K=512 (side r = k-half of W1F).
// Epilogue: e = exp(2*(v + b1[left only])) stored f16:
//   scalar-head slots (h<3): transposed [b][n][i]; label slots 6,7: [m][n].
// ---------------------------------------------------------------------------
__global__ __launch_bounds__(256) void gemm_lr_f16f(
    const unsigned short* __restrict__ X16F,
    const unsigned short* __restrict__ W1F, K1Args a,
    unsigned short* __restrict__ U) {
  const int side = blockIdx.z;
  const int h = side >> 1, r = side & 1;
  const float* __restrict__ bias = a.b1[h];
  const int tid = threadIdx.x;
  const int w = tid >> 6, lane = tid & 63;
  const int lm = lane & 15, q = lane >> 4;
  const int mtb = blockIdx.y * 4 + (w & 1) * 2;   // m-tile base (of 16)
  const int ntb = blockIdx.x * 4 + (w >> 1) * 2;  // n-tile base

  f32x4 acc[2][2];
#pragma unroll
  for (int mt = 0; mt < 2; ++mt)
#pragma unroll
    for (int nt = 0; nt < 2; ++nt) {
      acc[mt][nt].x = 0.f; acc[mt][nt].y = 0.f;
      acc[mt][nt].z = 0.f; acc[mt][nt].w = 0.f;
    }

  for (int kb = 0; kb < 16; ++kb) {
    UV4 af[2], bf[2];
#pragma unroll
    for (int mt = 0; mt < 2; ++mt)
      af[mt].u = *(const uint4*)(X16F +
          ((long)((mtb + mt) * 16 + kb) * 64 + lane) * 8);
#pragma unroll
    for (int nt = 0; nt < 2; ++nt)
      bf[nt].u = *(const uint4*)(W1F +
          ((long)((h * 32 + ntb + nt) * 32 + r * 16 + kb) * 64 + lane) * 8);
#pragma unroll
    for (int mt = 0; mt < 2; ++mt)
#pragma unroll
      for (int nt = 0; nt < 2; ++nt)
        acc[mt][nt] = __builtin_amdgcn_mfma_f32_16x16x32_f16(
            af[mt].h, bf[nt].h, acc[mt][nt], 0, 0, 0);
  }

  unsigned short* slot = U + side * SLOT;
  if (h < 3) {
#pragma unroll
    for (int nt = 0; nt < 2; ++nt) {
      const int n_out = (ntb + nt) * 16 + lm;
      const float bb = (r == 0) ? bias[n_out] : 0.0f;
#pragma unroll
      for (int mt = 0; mt < 2; ++mt) {
        const int m0r = (mtb + mt) * 16 + q * 4;
        const float e0 = __expf(2.0f * (acc[mt][nt].x + bb));
        const float e1 = __expf(2.0f * (acc[mt][nt].y + bb));
        const float e2 = __expf(2.0f * (acc[mt][nt].z + bb));
        const float e3 = __expf(2.0f * (acc[mt][nt].w + bb));
        uint2 pr;
        pr.x = pkrtz(e0, e1);
        pr.y = pkrtz(e2, e3);
        const int bi = m0r >> 7, il = m0r & 127;
        *(uint2*)(slot + bi * BSLOT + n_out * Ssz + il) = pr;
      }
    }
  } else {
#pragma unroll
    for (int nt = 0; nt < 2; ++nt) {
      const int n_out = (ntb + nt) * 16 + lm;
      const float bb = (r == 0) ? bias[n_out] : 0.0f;
#pragma unroll
      for (int mt = 0; mt < 2; ++mt) {
#pragma unroll
        for (int reg = 0; reg < 4; ++reg) {
          const int m_out = (mtb + mt) * 16 + q * 4 + reg;
          float v;
          if (reg == 0) v = acc[mt][nt].x;
          else if (reg == 1) v = acc[mt][nt].y;
          else if (reg == 2) v = acc[mt][nt].z;
          else v = acc[mt][nt].w;
          slot[m_out * Lsz + n_out] = f2h(__expf(2.0f * (v + bb)));
        }
      }
    }
  }
}

// ---------------------------------------------------------------------------
// Kernel 2: scalar heads, exp-identity, L-split x2 partials.
// acc = sum_l w2[l] * rcp(ea*eb + 1)  (2 fma + rcp per pair).
// grid (16 tiles, 8 b, 6 = h*2+half); block 256, tile 32x32, 2x2/thread.
// Partials (fp32) go to P (reuses dead W1F region).
// ---------------------------------------------------------------------------
__global__ __launch_bounds__(256) void pair_scalar5(
    const unsigned short* __restrict__ U,
    const float* __restrict__ w2a, const float* __restrict__ w2b,
    const float* __restrict__ w2c, float* __restrict__ P) {
  const int zh = blockIdx.z;
  const int h = zh >> 1, half = zh & 1;
  const int b = blockIdx.y;
  const int it = blockIdx.x >> 2, jt = blockIdx.x & 3;
  if (h == 0 && jt > it) return;   // span: strictly-upper tile unused
  const int i0 = it * 32, j0 = jt * 32;
  const int t = threadIdx.x;
  const int tj = t & 15, ti = t >> 4;

  const unsigned short* __restrict__ A  = U + (2 * h) * SLOT + b * BSLOT;
  const unsigned short* __restrict__ Bt = U + (2 * h + 1) * SLOT + b * BSLOT;
  const float* __restrict__ w2 = (h == 0) ? w2a : (h == 1 ? w2b : w2c);

  __shared__ unsigned short Ls[64][40];
  __shared__ unsigned short Rs[64][40];
  __shared__ float w2s[64];

  float acc00 = 0.f, acc01 = 0.f, acc10 = 0.f, acc11 = 0.f;
  const int sr = t >> 2;        // 0..63
  const int sc = (t & 3) * 8;   // 0,8,16,24
  const int lbase = half * 256;

  for (int lc = 0; lc < 256; lc += 64) {
    __syncthreads();
    const int gl = lbase + lc + sr;
    *(uint4*)&Ls[sr][sc] = *(const uint4*)(A + gl * Ssz + i0 + sc);
    *(uint4*)&Rs[sr][sc] = *(const uint4*)(Bt + gl * Ssz + j0 + sc);
    if (t < 64) w2s[t] = w2[lbase + lc + t];
    __syncthreads();
#pragma unroll 4
    for (int l = 0; l < 64; ++l) {
      const unsigned ua = *(const unsigned*)&Ls[l][ti * 2];
      const unsigned ub = *(const unsigned*)&Rs[l][tj * 2];
      const float ax = f16lo(ua), ay = f16hi(ua);
      const float bx = f16lo(ub), by = f16hi(ub);
      const float wv = w2s[l];
      acc00 = fmaf(wv, rcpf(fmaf(ax, bx, 1.0f)), acc00);
      acc01 = fmaf(wv, rcpf(fmaf(ax, by, 1.0f)), acc01);
      acc10 = fmaf(wv, rcpf(fmaf(ay, bx, 1.0f)), acc10);
      acc11 = fmaf(wv, rcpf(fmaf(ay, by, 1.0f)), acc11);
    }
  }

  float* Pp = P + ((long)(zh * Bsz + b)) * 16384;
  const int i = i0 + ti * 2, j = j0 + tj * 2;
  *(float2*)&Pp[(i + 0) * Ssz + j] = make_float2(acc00, acc01);
  *(float2*)&Pp[(i + 1) * Ssz + j] = make_float2(acc10, acc11);
}

// ---------------------------------------------------------------------------
// Kernel 2.5: combine partials: out = S - 2*(P0+P1) + b2; span symmetrized
// via out0[i][j] = v(max(i,j), min(i,j)). grid (128 i, 8 b, 3 h), 128 thr.
// ---------------------------------------------------------------------------
__global__ __launch_bounds__(128) void combine_scalar(
    const float* __restrict__ P,
    const float* __restrict__ w2a, const float* __restrict__ w2b,
    const float* __restrict__ w2c,
    const float* __restrict__ b2a, const float* __restrict__ b2b,
    const float* __restrict__ b2c,
    float* __restrict__ out) {
  const int h = blockIdx.z;
  const int b = blockIdx.y;
  const int i = blockIdx.x;
  const int t = threadIdx.x;   // j
  const float* __restrict__ w2 = (h == 0) ? w2a : (h == 1 ? w2b : w2c);
  const float bias = (h == 0) ? b2a[0] : (h == 1 ? b2b[0] : b2c[0]);

  __shared__ float red[128];
  float s = w2[t] + w2[t + 128] + w2[t + 256] + w2[t + 384];
  red[t] = s;
  __syncthreads();
  if (t < 64) red[t] += red[t + 64];
  __syncthreads();
  if (t < 32) red[t] += red[t + 32];
  __syncthreads();
  if (t < 16) red[t] += red[t + 16];
  __syncthreads();
  if (t < 8) red[t] += red[t + 8];
  __syncthreads();
  if (t < 4) red[t] += red[t + 4];
  __syncthreads();
  if (t < 2) red[t] += red[t + 2];
  __syncthreads();
  const float S = red[0] + red[1];

  const float* P0 = P + ((long)(h * 2 * Bsz + b)) * 16384;
  const float* P1 = P + ((long)((h * 2 + 1) * Bsz + b)) * 16384;
  int ii = i, jj = t;
  if (h == 0 && t > i) { ii = t; jj = i; }
  const float p = P0[ii * Ssz + jj] + P1[ii * Ssz + jj];
  out[h * OUTMAT + (b * Ssz + i) * Ssz + t] = S - 2.0f * p + bias;
}

// ---------------------------------------------------------------------------
// Kernel 3: label head, f16 MFMA, exp-identity, coalesced W2F frags,
// software pipeline. wg = 4 waves, 2 i's; wave = 16 j x 64 o, K=512.
// ---------------------------------------------------------------------------
__global__ __launch_bounds__(256) void pair_label6(
    const unsigned short* __restrict__ U,
    const unsigned short* __restrict__ W2F,
    const float* __restrict__ b2, float* __restrict__ out) {
  const int b = blockIdx.z;
  const int i0 = blockIdx.x * 2;
  const int tid = threadIdx.x;
  const int w = tid >> 6, lane = tid & 63;
  const int lm = lane & 15, q = lane >> 4;
  const int jb = blockIdx.y * 64 + w * 16;

  const unsigned short* __restrict__ L0 = U + 6 * SLOT + (b * Ssz + i0) * Lsz;
  const unsigned short* __restrict__ L1 = L0 + Lsz;
  const unsigned short* __restrict__ Rr = U + 7 * SLOT + (b * Ssz + jb + lm) * Lsz;
  float* out3 = out + 3 * OUTMAT;

  f32x4 acc[2][4];
#pragma unroll
  for (int ii = 0; ii < 2; ++ii)
#pragma unroll
    for (int nt = 0; nt < 4; ++nt) {
      acc[ii][nt].x = 0.f; acc[ii][nt].y = 0.f;
      acc[ii][nt].z = 0.f; acc[ii][nt].w = 0.f;
    }

  const int kq = q * 8;
  uint4 rc  = *(const uint4*)(Rr + kq);
  uint4 l0c = *(const uint4*)(L0 + kq);
  uint4 l1c = *(const uint4*)(L1 + kq);

#pragma unroll 1
  for (int kc = 0; kc < Lsz; kc += 32) {
    const int kn = ((kc + 32) & 511) + kq;
    uint4 rn  = *(const uint4*)(Rr + kn);
    uint4 l0n = *(const uint4*)(L0 + kn);
    uint4 l1n = *(const uint4*)(L1 + kn);
    UV4 bf[4];
    const int kb = kc >> 5;
#pragma unroll
    for (int nt = 0; nt < 4; ++nt)
      bf[nt].u = *(const uint4*)(W2F + ((long)(nt * 16 + kb) * 64 + lane) * 8);

    float rf[8] = {f16lo(rc.x), f16hi(rc.x), f16lo(rc.y), f16hi(rc.y),
                   f16lo(rc.z), f16hi(rc.z), f16lo(rc.w), f16hi(rc.w)};
    float a0[8] = {f16lo(l0c.x), f16hi(l0c.x), f16lo(l0c.y), f16hi(l0c.y),
                   f16lo(l0c.z), f16hi(l0c.z), f16lo(l0c.w), f16hi(l0c.w)};
    float a1[8] = {f16lo(l1c.x), f16hi(l1c.x), f16lo(l1c.y), f16hi(l1c.y),
                   f16lo(l1c.z), f16hi(l1c.z), f16lo(l1c.w), f16hi(l1c.w)};
    float h0[8], h1[8];
#pragma unroll
    for (int e = 0; e < 8; ++e) {
      h0[e] = fmaf(-2.0f, rcpf(fmaf(a0[e], rf[e], 1.0f)), 1.0f);
      h1[e] = fmaf(-2.0f, rcpf(fmaf(a1[e], rf[e], 1.0f)), 1.0f);
    }
    UV4 A0, A1;
    A0.u = make_uint4(pkrtz(h0[0], h0[1]), pkrtz(h0[2], h0[3]),
                      pkrtz(h0[4], h0[5]), pkrtz(h0[6], h0[7]));
    A1.u = make_uint4(pkrtz(h1[0], h1[1]), pkrtz(h1[2], h1[3]),
                      pkrtz(h1[4], h1[5]), pkrtz(h1[6], h1[7]));
#pragma unroll
    for (int nt = 0; nt < 4; ++nt) {
      acc[0][nt] = __builtin_amdgcn_mfma_f32_16x16x32_f16(
          A0.h, bf[nt].h, acc[0][nt], 0, 0, 0);
      acc[1][nt] = __builtin_amdgcn_mfma_f32_16x16x32_f16(
          A1.h, bf[nt].h, acc[1][nt], 0, 0, 0);
    }
    rc = rn; l0c = l0n; l1c = l1n;
  }

#pragma unroll
  for (int nt = 0; nt < 4; ++nt) {
    const int o = nt * 16 + lm;
    if (o >= Rsz) continue;
    const float bias = b2[o];
#pragma unroll
    for (int ii = 0; ii < 2; ++ii) {
#pragma unroll
      for (int reg = 0; reg < 4; ++reg) {
        const int j = jb + q * 4 + reg;
        const long base = ((long)((b * Ssz + i0 + ii) * Ssz) + j) * Rsz;
        float v;
        if (reg == 0) v = acc[ii][nt].x;
        else if (reg == 1) v = acc[ii][nt].y;
        else if (reg == 2) v = acc[ii][nt].z;
        else v = acc[ii][nt].w;
        out3[base + o] = v + bias;
      }
    }
  }
}

extern "C" void kernel_launch(void* const* d_in, const int* in_sizes, int n_in,
                              void* d_out, int out_size, void* d_ws,
                              size_t ws_size, hipStream_t stream) {
  (void)in_sizes; (void)n_in; (void)out_size; (void)ws_size;
  const float* x = (const float*)d_in[0];
  K1Args a;
  a.W1[0] = (const float*)d_in[1];  a.b1[0] = (const float*)d_in[2];
  a.W1[1] = (const float*)d_in[5];  a.b1[1] = (const float*)d_in[6];
  a.W1[2] = (const float*)d_in[9];  a.b1[2] = (const float*)d_in[10];
  a.W1[3] = (const float*)d_in[13]; a.b1[3] = (const float*)d_in[14];
  const float* w2a = (const float*)d_in[3];
  const float* b2a = (const float*)d_in[4];
  const float* w2b = (const float*)d_in[7];
  const float* b2b = (const float*)d_in[8];
  const float* w2c = (const float*)d_in[11];
  const float* b2c = (const float*)d_in[12];
  const float* W2l = (const float*)d_in[15];
  const float* b2l = (const float*)d_in[16];
  float* out = (float*)d_out;

  // ws layout (ushorts): [0, 8*SLOT): 8 f16 ea-slots (scalar heads transposed
  // [b][l][idx]; label 6,7 row-major [m][l]).
  // [8*SLOT, +2M u16): W1F (4MB, frag order) -- REUSED as fp32 partials P
  //   (3.1MB) by pair_scalar5/combine after gemm is done.
  // then X16F (1MB), then W2F (64KB).
  unsigned short* U    = (unsigned short*)d_ws;
  unsigned short* W1F  = U + 8 * SLOT;
  unsigned short* X16F = U + 8 * SLOT + 4 * (Lsz * D2);
  unsigned short* W2F  = U + 8 * SLOT + 5 * (Lsz * D2);
  float* P = (float*)W1F;

  prep_all<<<dim3(16, 16, 5), 256, 0, stream>>>(x, a, W1F, X16F);
  w2prep_f<<<16, 256, 0, stream>>>(W2l, W2F);
  gemm_lr_f16f<<<dim3(8, 16, 8), 256, 0, stream>>>(X16F, W1F, a, U);
  pair_scalar5<<<dim3(16, Bsz, 6), 256, 0, stream>>>(U, w2a, w2b, w2c, P);
  combine_scalar<<<dim3(Ssz, Bsz, 3), 128, 0, stream>>>(
      P, w2a, w2b, w2c, b2a, b2b, b2c, out);
  pair_label6<<<dim3(64, 2, Bsz), 256, 0, stream>>>(U, W2F, b2l, out);
}